// Round 1
// baseline (1745.209 us; speedup 1.0000x reference)
//
#include <hip/hip_runtime.h>
#include <math.h>

// Build conv kernel K[o,i,tap] folded with self-interaction at center tap.
// ws layout: Kw[(i*125 + tap)*64 + o], 64*125*64 floats = 2 MB.
__global__ __launch_bounds__(256) void build_K(
    const float* __restrict__ w_lin0,
    const float* __restrict__ w_lin1,
    const float* __restrict__ tp_weight,
    float* __restrict__ Kw)
{
    const int tap = blockIdx.x;                 // 0..124
    const int i1 = tap / 25, i2 = (tap / 5) % 5, i3 = tap % 5;
    // lattice point; sh-convention: x=axis0, y=axis1, z=axis2
    const float X = -1.0f + 0.5f * (float)i1;
    const float Y = -1.0f + 0.5f * (float)i2;
    const float Z = -1.0f + 0.5f * (float)i3;
    const float d = sqrtf(X*X + Y*Y + Z*Z);
    const float dinv = 1.0f / fmaxf(d, 1e-12f);
    const float vx = X * dinv, vy = Y * dinv, vz = Z * dinv;
    const float r2 = vx*vx + vy*vy + vz*vz;     // 1 except origin (0)

    __shared__ float wsh[1280];
    __shared__ float y1s[3];
    __shared__ float Qs[9];

    if (threadIdx.x == 0) {
        const float s3 = 1.7320508075688772f;
        const float s15 = 3.872983346207417f;
        y1s[0] = s3 * vy; y1s[1] = s3 * vz; y1s[2] = s3 * vx;
        float y2v0 = s15 * vx * vy;
        float y2v1 = s15 * vy * vz;
        float y2v2 = 1.118033988749895f * (3.0f * vz * vz - r2);
        float y2v3 = s15 * vx * vz;
        float y2v4 = 1.9364916731037085f * (vx * vx - vy * vy);
        const float INV10 = 0.31622776601683794f;  // 1/sqrt(10)
        const float INV30 = 0.18257418583505536f;  // 1/sqrt(30)
        // Q[a][c] = sum_m W3J121[a,m,c] * y2[m]  (symmetric)
        Qs[0] = -y2v2 * INV30 - y2v4 * INV10;
        Qs[4] =  2.0f * y2v2 * INV30;
        Qs[8] = -y2v2 * INV30 + y2v4 * INV10;
        Qs[1] = Qs[3] = y2v1 * INV10;
        Qs[2] = Qs[6] = y2v0 * INV10;
        Qs[5] = Qs[7] = y2v3 * INV10;
    }

    // radial embedding -> per-lattice weight vector w[1280]
    float emb[5];
    #pragma unroll
    for (int e = 0; e < 5; ++e) {
        float t = (d - 0.25f * (float)e) * 4.0f;   // (d - center)/sigma, sigma=0.25
        emb[e] = expf(-t * t) * (1.0f / 1.12f);
    }
    const float scale = cosf(3.14159265358979323846f * d) / 11.180339887498949f; // / 5^1.5

    for (int j = threadIdx.x; j < 1280; j += 256) {
        float s = 0.0f;
        #pragma unroll
        for (int e = 0; e < 5; ++e) s += emb[e] * tp_weight[e * 1280 + j];
        wsh[j] = scale * s;
    }
    __syncthreads();

    const float F0   = 0.17677669529663687f;  // sqrt(1/32)
    const float F1   = 0.25f;                 // sqrt(3/48)
    const float F0S3 = 0.10206207261596574f;  // F0/sqrt(3)
    const float F1S3 = 0.14433756729740646f;  // F1/sqrt(3)

    #pragma unroll 1
    for (int n = 0; n < 16; ++n) {
        int e = n * 256 + (int)threadIdx.x;   // 0..4095
        int o = e & 63, i = e >> 6;
        float Kv;
        if (o < 16) {
            if (i < 16) {
                Kv = F0 * wsh[0 * 256 + i * 16 + o];                       // b00
            } else {
                int u = (i - 16) / 3, a = (i - 16) % 3;
                Kv = F0S3 * y1s[a] * wsh[3 * 256 + u * 16 + o];            // b10
            }
        } else {
            int wcol = (o - 16) / 3, c = (o - 16) % 3;
            if (i < 16) {
                Kv = F1S3 * y1s[c] * wsh[1 * 256 + i * 16 + wcol];         // b01
            } else {
                int u = (i - 16) / 3, a = (i - 16) % 3;
                Kv = F1 * Qs[a * 3 + c] * wsh[4 * 256 + u * 16 + wcol];    // b11b
                if (a == c) Kv += F1S3 * wsh[2 * 256 + u * 16 + wcol];     // b11a
            }
        }
        // fold self-interaction (x10, since out = 0.1*conv_total) into center tap
        if (tap == 62) {
            if (o < 16) {
                if (i < 16) Kv += 2.5f * w_lin0[i * 16 + o];               // 10 * (1/4)
            } else if (i >= 16) {
                int v = (o - 16) / 3, m = (o - 16) % 3;
                int u = (i - 16) / 3, a = (i - 16) % 3;
                if (a == m) Kv += 2.5f * w_lin1[u * 16 + v];
            }
        }
        Kw[(i * 125 + tap) * 64 + o] = Kv;
    }
}

// Direct 3D conv, fp32. Block = (b, 4z x 4y x 32x tile, 16 output channels).
// Thread = 8 o x 4 consecutive x. LDS: per-input-channel x tile + K slice.
__global__ __launch_bounds__(256) void conv64(
    const float* __restrict__ x,
    const float* __restrict__ Kw,
    float* __restrict__ out)
{
    __shared__ __align__(16) float xt[2304];    // [8z][8y][36x]
    __shared__ __align__(16) float kt[2000];    // [125 tap][16 o]

    const int blk = blockIdx.x;
    const int osplit = blk & 3, yt = (blk >> 2) & 7, zt = (blk >> 5) & 7, b = blk >> 8;
    const int obase = osplit * 16;
    const int tid = (int)threadIdx.x;
    const int ohalf = tid >> 7;          // wave-uniform
    const int pg = tid & 127;
    const int xq = pg & 7, yl = (pg >> 3) & 3, zl = pg >> 5;
    const int x0 = xq * 4;
    const int z0 = zt * 4, y0 = yt * 4;

    float acc[8][4];
    #pragma unroll
    for (int a = 0; a < 8; ++a)
        #pragma unroll
        for (int p = 0; p < 4; ++p) acc[a][p] = 0.0f;

    #pragma unroll 1
    for (int i = 0; i < 64; ++i) {
        __syncthreads();
        const float* xc = x + (((size_t)(b * 64 + i)) << 15);  // 32^3 per channel
        #pragma unroll 1
        for (int l = tid; l < 2304; l += 256) {
            int lx = l % 36; int rem = l / 36; int ly = rem & 7; int lz = rem >> 3;
            int gz = z0 - 2 + lz, gy = y0 - 2 + ly, gx = lx - 2;
            float v = 0.0f;
            if ((unsigned)gz < 32u && (unsigned)gy < 32u && (unsigned)gx < 32u)
                v = xc[(gz << 10) + (gy << 5) + gx];
            xt[l] = v;
        }
        const float* kc = Kw + (size_t)i * 8000 + obase;
        #pragma unroll 1
        for (int l = tid; l < 2000; l += 256) {
            kt[l] = kc[(l >> 4) * 64 + (l & 15)];
        }
        __syncthreads();

        #pragma unroll 1
        for (int dz = 0; dz < 5; ++dz) {
            #pragma unroll 1
            for (int dy = 0; dy < 5; ++dy) {
                const float* xr = &xt[((zl + dz) * 8 + (yl + dy)) * 36 + x0];
                alignas(16) float xv[8];
                *reinterpret_cast<float4*>(&xv[0]) = *reinterpret_cast<const float4*>(&xr[0]);
                *reinterpret_cast<float4*>(&xv[4]) = *reinterpret_cast<const float4*>(&xr[4]);
                const float* kr = &kt[(dz * 5 + dy) * 80 + ohalf * 8];
                #pragma unroll
                for (int dx = 0; dx < 5; ++dx) {
                    alignas(16) float kv[8];
                    *reinterpret_cast<float4*>(&kv[0]) = *reinterpret_cast<const float4*>(&kr[dx * 16]);
                    *reinterpret_cast<float4*>(&kv[4]) = *reinterpret_cast<const float4*>(&kr[dx * 16 + 4]);
                    #pragma unroll
                    for (int oo = 0; oo < 8; ++oo)
                        #pragma unroll
                        for (int p = 0; p < 4; ++p)
                            acc[oo][p] += xv[dx + p] * kv[oo];
                }
            }
        }
    }

    const int gz = z0 + zl, gy = y0 + yl;
    #pragma unroll
    for (int oo = 0; oo < 8; ++oo) {
        const int o = obase + ohalf * 8 + oo;
        float4 r;
        r.x = 0.1f * acc[oo][0];
        r.y = 0.1f * acc[oo][1];
        r.z = 0.1f * acc[oo][2];
        r.w = 0.1f * acc[oo][3];
        *reinterpret_cast<float4*>(
            &out[(((size_t)(b * 64 + o)) << 15) + (gz << 10) + (gy << 5) + x0]) = r;
    }
}

extern "C" void kernel_launch(void* const* d_in, const int* in_sizes, int n_in,
                              void* d_out, int out_size, void* d_ws, size_t ws_size,
                              hipStream_t stream) {
    const float* x       = (const float*)d_in[0];
    const float* w_lin0  = (const float*)d_in[1];
    const float* w_lin1  = (const float*)d_in[2];
    const float* tp      = (const float*)d_in[3];
    float* Kw  = (float*)d_ws;
    float* out = (float*)d_out;

    build_K<<<125, 256, 0, stream>>>(w_lin0, w_lin1, tp, Kw);
    conv64<<<1024, 256, 0, stream>>>(x, Kw, out);
}

// Round 2
// 281.014 us; speedup vs baseline: 6.2104x; 6.2104x over previous
//
#include <hip/hip_runtime.h>
#include <math.h>

typedef __attribute__((ext_vector_type(8))) short bf16x8;
typedef __attribute__((ext_vector_type(4))) float f32x4;
typedef __attribute__((ext_vector_type(4))) unsigned int u32x4;

__device__ __forceinline__ unsigned f2bf(float f) {
    union { float f; unsigned u; } v; v.f = f;
    return (v.u + 0x7FFFu + ((v.u >> 16) & 1u)) >> 16;   // RTNE bf16
}

// Build conv kernel in bf16, layout Kb[tap][o][i] (i contiguous), taps 0..125
// with tap 125 all-zero (pad for tap-pairing). Self-interaction folded into
// center tap (62), x10 since out = 0.1*conv_total.
__global__ __launch_bounds__(256) void build_K(
    const float* __restrict__ w_lin0,
    const float* __restrict__ w_lin1,
    const float* __restrict__ tp_weight,
    unsigned short* __restrict__ Kb)
{
    const int tid = (int)threadIdx.x;
    const int tap = (int)blockIdx.x;            // 0..125
    if (tap == 125) {
        for (int n = tid; n < 4096; n += 256) Kb[125 * 4096 + n] = 0;
        return;
    }
    const int i1 = tap / 25, i2 = (tap / 5) % 5, i3 = tap % 5;
    const float X = -1.0f + 0.5f * (float)i1;
    const float Y = -1.0f + 0.5f * (float)i2;
    const float Z = -1.0f + 0.5f * (float)i3;
    const float d = sqrtf(X*X + Y*Y + Z*Z);
    const float dinv = 1.0f / fmaxf(d, 1e-12f);
    const float vx = X * dinv, vy = Y * dinv, vz = Z * dinv;
    const float r2 = vx*vx + vy*vy + vz*vz;

    __shared__ float wsh[1280];
    __shared__ float y1s[3];
    __shared__ float Qs[9];

    if (tid == 0) {
        const float s3 = 1.7320508075688772f;
        const float s15 = 3.872983346207417f;
        y1s[0] = s3 * vy; y1s[1] = s3 * vz; y1s[2] = s3 * vx;
        float y2v0 = s15 * vx * vy;
        float y2v1 = s15 * vy * vz;
        float y2v2 = 1.118033988749895f * (3.0f * vz * vz - r2);
        float y2v3 = s15 * vx * vz;
        float y2v4 = 1.9364916731037085f * (vx * vx - vy * vy);
        const float INV10 = 0.31622776601683794f;
        const float INV30 = 0.18257418583505536f;
        Qs[0] = -y2v2 * INV30 - y2v4 * INV10;
        Qs[4] =  2.0f * y2v2 * INV30;
        Qs[8] = -y2v2 * INV30 + y2v4 * INV10;
        Qs[1] = Qs[3] = y2v1 * INV10;
        Qs[2] = Qs[6] = y2v0 * INV10;
        Qs[5] = Qs[7] = y2v3 * INV10;
    }

    float emb[5];
    #pragma unroll
    for (int e = 0; e < 5; ++e) {
        float t = (d - 0.25f * (float)e) * 4.0f;
        emb[e] = expf(-t * t) * (1.0f / 1.12f);
    }
    const float scale = cosf(3.14159265358979323846f * d) / 11.180339887498949f;

    for (int j = tid; j < 1280; j += 256) {
        float s = 0.0f;
        #pragma unroll
        for (int e = 0; e < 5; ++e) s += emb[e] * tp_weight[e * 1280 + j];
        wsh[j] = scale * s;
    }
    __syncthreads();

    const float F0   = 0.17677669529663687f;
    const float F1   = 0.25f;
    const float F0S3 = 0.10206207261596574f;
    const float F1S3 = 0.14433756729740646f;

    #pragma unroll 1
    for (int n = 0; n < 16; ++n) {
        int e = n * 256 + tid;
        int o = e & 63, i = e >> 6;
        float Kv;
        if (o < 16) {
            if (i < 16) {
                Kv = F0 * wsh[0 * 256 + i * 16 + o];
            } else {
                int u = (i - 16) / 3, a = (i - 16) % 3;
                Kv = F0S3 * y1s[a] * wsh[3 * 256 + u * 16 + o];
            }
        } else {
            int wcol = (o - 16) / 3, c = (o - 16) % 3;
            if (i < 16) {
                Kv = F1S3 * y1s[c] * wsh[1 * 256 + i * 16 + wcol];
            } else {
                int u = (i - 16) / 3, a = (i - 16) % 3;
                Kv = F1 * Qs[a * 3 + c] * wsh[4 * 256 + u * 16 + wcol];
                if (a == c) Kv += F1S3 * wsh[2 * 256 + u * 16 + wcol];
            }
        }
        if (tap == 62) {
            if (o < 16) {
                if (i < 16) Kv += 2.5f * w_lin0[i * 16 + o];
            } else if (i >= 16) {
                int v = (o - 16) / 3, m = (o - 16) % 3;
                int u = (i - 16) / 3, a = (i - 16) % 3;
                if (a == m) Kv += 2.5f * w_lin1[u * 16 + v];
            }
        }
        Kb[(tap * 64 + o) * 64 + i] = (unsigned short)f2bf(Kv);
    }
}

// Implicit-GEMM conv via MFMA 16x16x32 bf16.
// Block: 256 thr = 4 waves; tile = 4z x 8y x 8x = 256 pos, all 64 o.
// Wave = one z-plane (64 pos). K per MFMA = 16ch x 2taps; 63 tap-pairs,
// 4 channel stages. x halo staged in LDS bf16 (48B/pos pad), Kb frags from
// global (L2) with 1-pair register double-buffer. No barriers in tap loop.
__global__ __launch_bounds__(256) void conv_mfma(
    const float* __restrict__ x,
    const unsigned short* __restrict__ Kb,
    float* __restrict__ out)
{
    __shared__ __align__(16) char xs[55296];    // [8z][12y][12x] * 48B (16ch bf16 + 8 pad)
    __shared__ int dOff[126];

    const int tid = (int)threadIdx.x;
    const int blk = (int)blockIdx.x;
    const int xt = blk & 3, yt = (blk >> 2) & 3, zt = (blk >> 4) & 7, b = blk >> 7;
    const int lane = tid & 63, wv = tid >> 6;

    if (tid < 126) {
        int t = (tid == 125) ? 124 : tid;       // pad tap aliases tap 124 (B=0 kills it)
        dOff[tid] = ((t / 25) * 144 + ((t / 5) % 5) * 12 + (t % 5)) * 48;
    }

    const int r = lane & 15, g = lane >> 4;
    const int thalf = g >> 1, chslot = g & 1;
    const int ldsBase = wv * 6912 + (r >> 3) * 576 + (r & 7) * 48 + chslot * 16;
    const char* kbl = (const char*)Kb + r * 128 + thalf * 8192 + chslot * 16;

    f32x4 acc[4][4];
    #pragma unroll
    for (int i = 0; i < 4; ++i)
        #pragma unroll
        for (int j = 0; j < 4; ++j) acc[i][j] = (f32x4)0.0f;

    const int gz0 = zt * 4 - 2, gy0 = yt * 8 - 2, gx0 = xt * 8 - 2;

    #pragma unroll 1
    for (int stage = 0; stage < 4; ++stage) {
        __syncthreads();
        // stage 16 channels of halo tile: 1152 pos x 2 slots of 8ch
        #pragma unroll 1
        for (int it = 0; it < 9; ++it) {
            int tau = tid + it * 256;           // 0..2303
            int pos = tau >> 1, slot = tau & 1;
            int hz = pos / 144; int rem = pos - hz * 144;
            int hy = rem / 12;  int hx = rem - hy * 12;
            int gz = gz0 + hz, gy = gy0 + hy, gx = gx0 + hx;
            bool ok = ((unsigned)gz < 32u) && ((unsigned)gy < 32u) && ((unsigned)gx < 32u);
            int goff = ok ? ((gz << 10) + (gy << 5) + gx) : 0;
            const float* xp = x + (((size_t)(b * 64 + stage * 16 + slot * 8)) << 15) + goff;
            float f[8];
            #pragma unroll
            for (int jj = 0; jj < 8; ++jj) f[jj] = xp[(size_t)jj << 15];
            u32x4 dv;
            #pragma unroll
            for (int jj = 0; jj < 4; ++jj) {
                unsigned lo = ok ? f2bf(f[2 * jj]) : 0u;
                unsigned hi = ok ? f2bf(f[2 * jj + 1]) : 0u;
                dv[jj] = lo | (hi << 16);
            }
            *(u32x4*)&xs[pos * 48 + slot * 16] = dv;
        }
        __syncthreads();

        const char* kbs = kbl + stage * 32;

        bf16x8 A0[4], A1[4];
        #pragma unroll
        for (int mo = 0; mo < 4; ++mo)
            A0[mo] = *(const bf16x8*)(kbs + mo * 2048);

#define COMPUTE(P, AF)                                                        \
        {                                                                     \
            int doff = dOff[2 * (P) + thalf];                                 \
            bf16x8 xf[4];                                                     \
            _Pragma("unroll")                                                 \
            for (int np = 0; np < 4; ++np)                                    \
                xf[np] = *(const bf16x8*)&xs[ldsBase + np * 1152 + doff];     \
            _Pragma("unroll")                                                 \
            for (int mo = 0; mo < 4; ++mo)                                    \
                _Pragma("unroll")                                             \
                for (int np = 0; np < 4; ++np)                                \
                    acc[mo][np] = __builtin_amdgcn_mfma_f32_16x16x32_bf16(    \
                        AF[mo], xf[np], acc[mo][np], 0, 0, 0);                \
        }

        #pragma unroll 1
        for (int pp = 0; pp < 31; ++pp) {
            int p0 = 2 * pp;
            #pragma unroll
            for (int mo = 0; mo < 4; ++mo)
                A1[mo] = *(const bf16x8*)(kbs + (p0 + 1) * 16384 + mo * 2048);
            COMPUTE(p0, A0);
            #pragma unroll
            for (int mo = 0; mo < 4; ++mo)
                A0[mo] = *(const bf16x8*)(kbs + (p0 + 2) * 16384 + mo * 2048);
            COMPUTE(p0 + 1, A1);
        }
        COMPUTE(62, A0);
#undef COMPUTE
    }

    // epilogue: D row = o-in-tile = g*4+reg, col = pos-in-tile = r
    const int oz = zt * 4 + wv;
    #pragma unroll
    for (int mo = 0; mo < 4; ++mo) {
        #pragma unroll
        for (int reg = 0; reg < 4; ++reg) {
            int o = mo * 16 + g * 4 + reg;
            float* op = out + (((size_t)(b * 64 + o)) << 15) + (oz << 10);
            #pragma unroll
            for (int np = 0; np < 4; ++np) {
                int ly = np * 2 + (r >> 3), lx = r & 7;
                op[((yt * 8 + ly) << 5) + (xt * 8 + lx)] = 0.1f * acc[mo][np][reg];
            }
        }
    }
}

extern "C" void kernel_launch(void* const* d_in, const int* in_sizes, int n_in,
                              void* d_out, int out_size, void* d_ws, size_t ws_size,
                              hipStream_t stream) {
    const float* x       = (const float*)d_in[0];
    const float* w_lin0  = (const float*)d_in[1];
    const float* w_lin1  = (const float*)d_in[2];
    const float* tp      = (const float*)d_in[3];
    unsigned short* Kb = (unsigned short*)d_ws;    // 126*64*64*2B ~= 1 MB
    float* out = (float*)d_out;

    build_K<<<126, 256, 0, stream>>>(w_lin0, w_lin1, tp, Kb);
    conv_mfma<<<512, 256, 0, stream>>>(x, Kb, out);
}